// Round 9
// baseline (475.944 us; speedup 1.0000x reference)
//
#include <hip/hip_runtime.h>
#include <hip/hip_cooperative_groups.h>

namespace cg = cooperative_groups;

typedef __bf16 bf16x8 __attribute__((ext_vector_type(8)));
typedef float f32x4 __attribute__((ext_vector_type(4)));

#define B_CHUNK 64      // edge chunks (counting sort)
#define R_RANGE 4       // dst ranges per chunk (LDS hist = 25 KB)
#define GRID_F 768      // cooperative grid: 3 blocks/CU x 256 CUs (LDS-limit 6/CU)

__device__ __forceinline__ float exp2_fast(float x){
#if __has_builtin(__builtin_amdgcn_exp2f)
  return __builtin_amdgcn_exp2f(x);
#else
  return __expf(x * 0.69314718055994531f);
#endif
}
template<int CTRL>
__device__ __forceinline__ float dpp_add(float x){
  union { float f; int i; } a, b;
  a.f = x;
  b.i = __builtin_amdgcn_mov_dpp(a.i, CTRL, 0xF, 0xF, true);
  return x + b.f;
}
__device__ __forceinline__ float sum4(float x){      // reduce within quad (one head)
  x = dpp_add<0xB1>(x);    // quad_perm [1,0,3,2]
  x = dpp_add<0x4E>(x);    // quad_perm [2,3,0,1]
  return x;
}
// single-instruction packed f32->bf16 (RNE), gfx950
__device__ __forceinline__ unsigned int cvt_pk_bf16(float lo, float hi){
  unsigned int r;
  asm("v_cvt_pk_bf16_f32 %0, %1, %2" : "=v"(r) : "v"(lo), "v"(hi));
  return r;
}
__device__ __forceinline__ unsigned short f2bf1(float f){
  return (unsigned short)cvt_pk_bf16(f, f);
}
__device__ __forceinline__ bf16x8 ld_bf8(const unsigned short* p){
  union { uint4 u; bf16x8 v; } c;
  c.u = *reinterpret_cast<const uint4*>(p);
  return c.v;
}
__device__ __forceinline__ bf16x8 ld_f32_to_bf8(const float* p){
  float4 lo = *reinterpret_cast<const float4*>(p);
  float4 hi = *reinterpret_cast<const float4*>(p + 4);
  union { unsigned int u[4]; bf16x8 v; } c;
  c.u[0] = cvt_pk_bf16(lo.x, lo.y);
  c.u[1] = cvt_pk_bf16(lo.z, lo.w);
  c.u[2] = cvt_pk_bf16(hi.x, hi.y);
  c.u[3] = cvt_pk_bf16(hi.z, hi.w);
  return c.v;
}

struct FArgs {
  const int* ntype; int* tcur; int* nbt; int Npad; int N;
  const float* subW; const float* neighW;
  unsigned short* wts; unsigned short* wtn;
  const int* ei; int E;
  unsigned short* hist; unsigned short* rank; int RNG; int HR;
  const float* h_mat; const float* hsW; const float* hsb;
  const float* hnW; const float* hnb;
  float2* hs2; char* hnc;
  const float* X; const float* sub_b; const float* neigh_b;
  float* q; char* kkc;
  unsigned short* bucket; int* deg;
};

// ---------- Phase A: [S1 hist+rank | W transpose->bf16 | h proj] ----------
__device__ void phaseA(const FArgs& a, int bid, int nb){
  __shared__ unsigned int lsh[6272];   // packed u16 bins, 25 KB (bins = RNG/2 <= 6250)
  const int SB1 = B_CHUNK * R_RANGE;   // 256
  const int WB  = 512;
  const int HB  = (a.N*32 + 255) >> 8;
  const int TA  = SB1 + WB + HB;
  if (bid == 0 && threadIdx.x < 4) a.tcur[threadIdx.x] = 0;   // read in phase B (post-sync)
  for (int t = bid; t < TA; t += nb){
    if (t < SB1){
      // histogram chunk cb, dst range r; atomic old value = intra-chunk rank
      int cb = t & (B_CHUNK - 1);
      int r  = t >> 6;
      int lo = r * a.RNG;
      int bins = a.RNG >> 1;
      __syncthreads();
      for (int i = threadIdx.x; i < bins; i += 256) lsh[i] = 0;
      __syncthreads();
      int C = (a.E + B_CHUNK - 1) / B_CHUNK;
      int e0 = cb * C;
      int e1 = e0 + C; if (e1 > a.E) e1 = a.E;
      for (int i = e0 + threadIdx.x; i < e1; i += 256){
        int d = a.ei[a.E + i] - lo;
        if ((unsigned)d < (unsigned)a.RNG){
          unsigned old = atomicAdd(&lsh[d >> 1], (d & 1) ? 65536u : 1u);
          a.rank[i] = (unsigned short)((old >> ((d & 1) << 4)) & 0xffffu);
        }
      }
      __syncthreads();
      unsigned int* hrow =
          reinterpret_cast<unsigned int*>(a.hist + (size_t)cb*a.HR + lo);
      for (int i = threadIdx.x; i < bins; i += 256) hrow[i] = lsh[i];
      __syncthreads();
    } else if (t < SB1 + WB){
      // W transpose -> bf16 [t][o][k]   (exactly WB*256 = 131072 elements)
      int i = (t - SB1)*256 + threadIdx.x;
      int w = i >> 16;
      int r = i & 65535;
      int tt = r >> 14;
      int rem = r & 16383;
      int o = rem >> 7;
      int kd = rem & 127;
      const float* src = w ? a.neighW : a.subW;
      unsigned short* dstp = w ? a.wtn : a.wts;
      dstp[(tt << 14) + (o << 7) + kd] = f2bf1(src[(tt << 14) + (kd << 7) + o]);
    } else {
      // h projections: 2 cols/thread -> hs2 (f32x2) and hnc (packed bf16 dword)
      int i = (t - SB1 - WB)*256 + threadIdx.x;
      if (i < a.N*32){
        int n = i >> 5, l = i & 31;
        const float* hm = a.h_mat + (size_t)n*8;
        const float2* hsW2 = reinterpret_cast<const float2*>(a.hsW);
        const float2* hnW2 = reinterpret_cast<const float2*>(a.hnW);
        float s0=0.f, s1=0.f, n0=0.f, n1=0.f;
        #pragma unroll
        for (int d = 0; d < 8; ++d){
          float hv = hm[d];
          float2 ws2 = hsW2[d*32 + l];
          float2 wn2 = hnW2[d*32 + l];
          s0 += hv * ws2.x; s1 += hv * ws2.y;
          n0 += hv * wn2.x; n1 += hv * wn2.y;
        }
        float2 bs = reinterpret_cast<const float2*>(a.hsb)[l];
        float2 bn = reinterpret_cast<const float2*>(a.hnb)[l];
        a.hs2[(size_t)i] = make_float2(s0 + bs.x, s1 + bs.y);
        *reinterpret_cast<unsigned int*>(a.hnc + (size_t)n*128 + l*4)
            = cvt_pk_bf16(n0 + bn.x, n1 + bn.y);
      }
    }
  }
}

// ---------- Phase B: [per-dst chunk-scan -> bases + deg | nbt type-bucket] ----------
__device__ void phaseB(const FArgs& a, int bid, int nb){
  const int SCB = (a.N + 255) >> 8;
  const int TB  = SCB * 2;
  for (int t = bid; t < TB; t += nb){
    if (t < SCB){
      int d = t*256 + threadIdx.x;
      if (d < a.N){
        unsigned run = 0;
        #pragma unroll 4
        for (int c = 0; c < B_CHUNK; ++c){
          unsigned short* p = a.hist + (size_t)c*a.HR + d;
          unsigned v = *p;
          *p = (unsigned short)run;
          run += v;
        }
        a.deg[d] = (int)run;
      }
    } else {
      int i = (t - SCB)*256 + threadIdx.x;
      if (i < a.N){
        int lane = threadIdx.x & 63;
        int myt = a.ntype[i];
        unsigned long long below = (lane == 0) ? 0ull : ((~0ull) >> (64 - lane));
        #pragma unroll
        for (int tt = 0; tt < 4; ++tt){
          unsigned long long mask = __ballot(myt == tt);
          if (mask){
            int leader = __ffsll((long long)mask) - 1;
            int base = 0;
            if (lane == leader) base = atomicAdd(&a.tcur[tt], __popcll(mask));
            base = __shfl(base, leader);
            if (myt == tt){
              int pos = base + __popcll(mask & below);
              a.nbt[tt*a.Npad + pos] = i;
            }
          }
        }
      }
    }
  }
}

// ---------- Phase C: [atomic-free scatter | MFMA projections] ----------
__device__ void phaseC(const FArgs& a, int bid, int nb){
  const int SB3 = 512;
  const int MBX = ((a.N + 63) >> 6) + 4;
  const int TC  = SB3 + MBX;
  for (int t = bid; t < TC; t += nb){
    if (t < SB3){
      // scatter: pos = scanned base (this chunk) + intra-chunk rank. No atomics.
      int cb = t >> 3;
      int sub = t & 7;
      int C = (a.E + B_CHUNK - 1) / B_CHUNK;
      int seg = (C + 7) >> 3;
      int s0 = sub*seg;
      int s1 = s0 + seg; if (s1 > C) s1 = C;
      int e0 = cb*C + s0;
      int e1 = cb*C + s1; if (e1 > a.E) e1 = a.E;
      const unsigned short* hrow = a.hist + (size_t)cb*a.HR;
      for (int i = e0 + threadIdx.x; i < e1; i += 256){
        int d = a.ei[a.E + i];
        int pos = (int)hrow[d] + (int)a.rank[i];
        if (pos < 128) a.bucket[(size_t)d*128 + pos] = (unsigned short)a.ei[i];
      }
    } else {
      // MFMA 16x16x32 bf16, swapped operands: C[row=o][col=node];
      // lane owns 4 consecutive output dims of one node -> float4 / 8B stores.
      int b = t - SB3;
      int ts = -1, chunk = 0, acc = 0;
      #pragma unroll
      for (int tt = 0; tt < 4; ++tt){
        int cnt = a.tcur[tt];
        int nc = (cnt + 63) >> 6;
        if (ts < 0 && b < acc + nc){ ts = tt; chunk = b - acc; }
        acc += nc;
      }
      if (ts >= 0){
        int lane = threadIdx.x & 63;
        int w = threadIdx.x >> 6;
        int quad = lane >> 4, l16 = lane & 15;
        int cnt = a.tcur[ts];
        int p = chunk*64 + w*16 + l16;
        bool ok = p < cnt;
        int nid = a.nbt[ts*a.Npad + (ok ? p : 0)];
        bf16x8 xb[4];
        #pragma unroll
        for (int kk = 0; kk < 4; ++kk)
          xb[kk] = ld_f32_to_bf8(a.X + (size_t)nid*128 + kk*32 + quad*8);
        #pragma unroll
        for (int pj = 0; pj < 2; ++pj){
          const unsigned short* Wt = pj ? a.wtn : a.wts;
          const float* bias = pj ? a.neigh_b : a.sub_b;
          #pragma unroll
          for (int ot = 0; ot < 8; ++ot){
            f32x4 c = {0.f, 0.f, 0.f, 0.f};
            #pragma unroll
            for (int kk = 0; kk < 4; ++kk){
              bf16x8 wa = ld_bf8(Wt + ((size_t)ts << 14) + ((size_t)(ot*16 + l16) << 7)
                                    + kk*32 + quad*8);
              c = __builtin_amdgcn_mfma_f32_16x16x32_bf16(wa, xb[kk], c, 0, 0, 0);
            }
            int o0 = ot*16 + quad*4;
            float4 b4 = *reinterpret_cast<const float4*>(bias + ts*128 + o0);
            if (ok){
              if (pj == 0){
                float4 v = make_float4(c[0]+b4.x, c[1]+b4.y, c[2]+b4.z, c[3]+b4.w);
                *reinterpret_cast<float4*>(a.q + (size_t)nid*128 + o0) = v;
              } else {
                uint2 pk;
                pk.x = cvt_pk_bf16(c[0]+b4.x, c[1]+b4.y);
                pk.y = cvt_pk_bf16(c[2]+b4.z, c[3]+b4.w);
                *reinterpret_cast<uint2*>(a.kkc + ((size_t)nid << 8) + (size_t)(o0 << 1)) = pk;
              }
            }
          }
        }
      }
    }
  }
}

// ---------- single cooperative dispatch: A -> sync -> B -> sync -> C ----------
__global__ __launch_bounds__(256) void k_all(FArgs a){
  cg::grid_group g = cg::this_grid();
  phaseA(a, blockIdx.x, gridDim.x);
  g.sync();
  phaseB(a, blockIdx.x, gridDim.x);
  g.sync();
  phaseC(a, blockIdx.x, gridDim.x);
}
// fallback (non-cooperative) wrappers
__global__ __launch_bounds__(256) void kA(FArgs a){ phaseA(a, blockIdx.x, gridDim.x); }
__global__ __launch_bounds__(256) void kB(FArgs a){ phaseB(a, blockIdx.x, gridDim.x); }
__global__ __launch_bounds__(256) void kC(FArgs a){ phaseC(a, blockIdx.x, gridDim.x); }

// ---------- k_edge: per-dst-node wave, TWO edges per iteration (half-wave each).
//   UNCHANGED from R8 (75 us, VALUBusy 91%). ----------
__global__ __launch_bounds__(256) void k_edge(const float* q, const char* kkc,
      const char* hnc, const float2* hs2, const int* degA,
      const unsigned short* bucket, const int* ntype,
      const float* rel_att, const float* rel_h_att,
      const float* ln_g, const float* ln_b,
      float* out, int N){
  int wid = (blockIdx.x*blockDim.x + threadIdx.x) >> 6;
  if (wid >= N) return;
  int lane = threadIdx.x & 63;
  int l = lane & 31;
  int half = (lane >> 5) & 1;
  int t4 = l & 3, head = l >> 2;
  const float TLOG2E = 2.8853900817779268f;   // 2*log2(e)
  float4 qv = *reinterpret_cast<const float4*>(q + (size_t)wid*128 + l*4);
  float qe0 = qv.x*TLOG2E, qe1 = qv.y*TLOG2E, qe2 = qv.z*TLOG2E, qe3 = qv.w*TLOG2E;
  float2 hv = hs2[(size_t)wid*32 + l];
  float he0 = hv.x*TLOG2E, he1 = hv.y*TLOG2E;
  int st = ntype[wid];
  int rb = st*8 + head;
  float4 ra = *reinterpret_cast<const float4*>(rel_att + rb*16 + t4*4);
  float2 rh = *reinterpret_cast<const float2*>(rel_h_att + rb*8 + t4*2);
  float c0 = -0.5f*ra.x, c1 = -0.5f*ra.y, c2 = -0.5f*ra.z, c3 = -0.5f*ra.w;
  float cs = 0.25f*(ra.x + ra.y + ra.z + ra.w);
  const float HSC = 0.35355339059327373f * 1.4426950408889634f;
  float rh0 = rh.x*HSC, rh1 = rh.y*HSC;
  float ch0 = -2.f*rh0, ch1 = -2.f*rh1, chs = rh0 + rh1;
  float s = 0.f, a0 = 0.f, a1 = 0.f, a2 = 0.f, a3 = 0.f;

  int deg = __builtin_amdgcn_readfirstlane(degA[wid]);
  if (deg > 128) deg = 128;
  unsigned bkt = reinterpret_cast<const unsigned*>(bucket)[(size_t)wid*64 + lane];
  int niter = (deg + 1) >> 1;
  const char* kk_l = kkc + l*8;
  const char* hn_l = hnc + l*4;

  struct KH { uint2 k; unsigned h; };
  auto lp = [&](int g)->KH {
    int gg = g < niter ? g : 0;
    unsigned v = (unsigned)__builtin_amdgcn_readlane((int)bkt, gg);
    int sA = (int)(v & 0xffffu);
    int sB = (2*gg + 1 < deg) ? (int)(v >> 16) : sA;
    int sy = half ? sB : sA;
    KH r;
    r.k = *reinterpret_cast<const uint2*>(kk_l + ((size_t)(unsigned)sy << 8));
    r.h = *reinterpret_cast<const unsigned*>(hn_l + ((size_t)(unsigned)sy << 7));
    return r;
  };
  auto pr = [&](KH P, int g){
    union { unsigned u; float f; } k0,k1,k2,k3,h0,h1;
    k0.u = P.k.x << 16; k1.u = P.k.x & 0xffff0000u;
    k2.u = P.k.y << 16; k3.u = P.k.y & 0xffff0000u;
    h0.u = P.h << 16;   h1.u = P.h & 0xffff0000u;
    float e0 = exp2_fast(qe0*k0.f), e1 = exp2_fast(qe1*k1.f);
    float e2 = exp2_fast(qe2*k2.f), e3 = exp2_fast(qe3*k3.f);
    float f0 = exp2_fast(he0*h0.f), f1 = exp2_fast(he1*h1.f);
    float r0 = __builtin_amdgcn_rcpf(e0 + 1.f), r1 = __builtin_amdgcn_rcpf(e1 + 1.f);
    float r2 = __builtin_amdgcn_rcpf(e2 + 1.f), r3 = __builtin_amdgcn_rcpf(e3 + 1.f);
    float g0 = __builtin_amdgcn_rcpf(f0 + 1.f), g1 = __builtin_amdgcn_rcpf(f1 + 1.f);
    float pp = fmaf(c0,r0, fmaf(c1,r1, fmaf(c2,r2, fmaf(c3,r3, cs))));
    float ph = fmaf(ch0,g0, fmaf(ch1,g1, chs));
    pp = sum4(pp);
    ph = sum4(ph);
    float w = exp2_fast(pp * ph);
    w = (2*g + half < deg) ? w : 0.f;
    s += w;
    a0 = fmaf(w, k0.f, a0); a1 = fmaf(w, k1.f, a1);
    a2 = fmaf(w, k2.f, a2); a3 = fmaf(w, k3.f, a3);
  };

  if (niter > 0){
    KH A = lp(0);
    KH B = lp(1);
    for (int g = 0; g < niter; g += 2){
      KH C = lp(g+2);
      pr(A, g);
      KH D = lp(g+3);
      if (g+1 < niter) pr(B, g+1);
      A = C; B = D;
    }
  }
  s  += __shfl_xor(s, 32);
  a0 += __shfl_xor(a0, 32); a1 += __shfl_xor(a1, 32);
  a2 += __shfl_xor(a2, 32); a3 += __shfl_xor(a3, 32);

  float inv = 1.0f / (s + 1e-16f);
  float x0 = a0*inv, x1 = a1*inv, x2 = a2*inv, x3 = a3*inv;
  const float IS2 = 0.70710678118654752f;
  x0 = 0.5f*x0*(1.f + erff(x0*IS2));
  x1 = 0.5f*x1*(1.f + erff(x1*IS2));
  x2 = 0.5f*x2*(1.f + erff(x2*IS2));
  x3 = 0.5f*x3*(1.f + erff(x3*IS2));
  float sm = x0+x1+x2+x3;
  float sq = x0*x0 + x1*x1 + x2*x2 + x3*x3;
  #pragma unroll
  for (int d = 1; d < 32; d <<= 1){ sm += __shfl_xor(sm, d); sq += __shfl_xor(sq, d); }
  float mu = sm * (1.f/128.f);
  float var = fmaxf(sq * (1.f/128.f) - mu*mu, 0.f);
  float r = rsqrtf(var + 1e-5f);
  if (half == 0){
    float4 g4 = *reinterpret_cast<const float4*>(ln_g + l*4);
    float4 b4 = *reinterpret_cast<const float4*>(ln_b + l*4);
    float4 o4 = make_float4((x0-mu)*r*g4.x + b4.x, (x1-mu)*r*g4.y + b4.y,
                            (x2-mu)*r*g4.z + b4.z, (x3-mu)*r*g4.w + b4.w);
    *reinterpret_cast<float4*>(out + (size_t)wid*128 + l*4) = o4;
  }
}

extern "C" void kernel_launch(void* const* d_in, const int* in_sizes, int n_in,
                              void* d_out, int out_size, void* d_ws, size_t ws_size,
                              hipStream_t stream) {
  const float* meta_xs  = (const float*)d_in[0];
  const int*   node_type= (const int*)d_in[1];
  const int*   edge_idx = (const int*)d_in[2];
  const float* h_mat    = (const float*)d_in[3];
  const float* sub_W    = (const float*)d_in[4];
  const float* sub_b    = (const float*)d_in[5];
  const float* neigh_W  = (const float*)d_in[6];
  const float* neigh_b  = (const float*)d_in[7];
  const float* hsub_W   = (const float*)d_in[8];
  const float* hsub_b   = (const float*)d_in[9];
  const float* hneigh_W = (const float*)d_in[10];
  const float* hneigh_b = (const float*)d_in[11];
  const float* rel_att  = (const float*)d_in[12];
  const float* rel_hatt = (const float*)d_in[13];
  const float* ln_g     = (const float*)d_in[14];
  const float* ln_b     = (const float*)d_in[15];

  const int N = in_sizes[0] / 128;
  const int E = in_sizes[2] / 2;
  const int Npad = (N + 63) & ~63;
  const int RNG = (((N + R_RANGE - 1) / R_RANGE) + 1) & ~1;   // even range width
  const int HR  = RNG * R_RANGE;                              // hist row stride (u16)

  char* wbase = (char*)d_ws;
  size_t o = 0;
  auto carve = [&](size_t bytes)->char* {
    char* p = wbase + o;
    o = (o + bytes + 255) & ~(size_t)255;
    return p;
  };
  float*          q      = (float*)carve((size_t)N*128*4);
  char*           kkc    = carve((size_t)N*256);                 // k bf16[128] per node
  char*           hnc    = carve((size_t)N*128);                 // h bf16[64]  per node
  float2*         hs2    = (float2*)carve((size_t)N*32*8);
  unsigned short* bucket = (unsigned short*)carve((size_t)N*128*2);
  unsigned short* hist   = (unsigned short*)carve((size_t)B_CHUNK*HR*2);
  unsigned short* rank   = (unsigned short*)carve((size_t)E*2);
  int*            deg    = (int*)carve((size_t)N*4);
  int*            tmeta  = (int*)carve(64);                      // tcur[4]
  int*            nbt    = (int*)carve((size_t)4*Npad*4);
  unsigned short* wts    = (unsigned short*)carve((size_t)4*128*128*2);
  unsigned short* wtn    = (unsigned short*)carve((size_t)4*128*128*2);
  if (o > ws_size) return;

  FArgs fa;
  fa.ntype = node_type; fa.tcur = tmeta; fa.nbt = nbt; fa.Npad = Npad; fa.N = N;
  fa.subW = sub_W; fa.neighW = neigh_W; fa.wts = wts; fa.wtn = wtn;
  fa.ei = edge_idx; fa.E = E;
  fa.hist = hist; fa.rank = rank; fa.RNG = RNG; fa.HR = HR;
  fa.h_mat = h_mat; fa.hsW = hsub_W; fa.hsb = hsub_b;
  fa.hnW = hneigh_W; fa.hnb = hneigh_b;
  fa.hs2 = hs2; fa.hnc = hnc;
  fa.X = meta_xs; fa.sub_b = sub_b; fa.neigh_b = neigh_b;
  fa.q = q; fa.kkc = kkc;
  fa.bucket = bucket; fa.deg = deg;

  void* params[1] = { (void*)&fa };
  hipError_t err = hipLaunchCooperativeKernel(
      reinterpret_cast<void*>(k_all), dim3(GRID_F), dim3(256), params, 0, stream);
  if (err != hipSuccess){
    (void)hipGetLastError();   // clear sticky error; fall back to 3 normal launches
    kA<<<GRID_F, 256, 0, stream>>>(fa);
    kB<<<GRID_F, 256, 0, stream>>>(fa);
    kC<<<GRID_F, 256, 0, stream>>>(fa);
  }
  k_edge<<<(N+3)/4, 256, 0, stream>>>(q, kkc, hnc, hs2, deg, bucket, node_type,
                                      rel_att, rel_hatt, ln_g, ln_b,
                                      (float*)d_out, N);
}

// Round 10
// 291.446 us; speedup vs baseline: 1.6330x; 1.6330x over previous
//
#include <hip/hip_runtime.h>

typedef __bf16 bf16x8 __attribute__((ext_vector_type(8)));
typedef float f32x4 __attribute__((ext_vector_type(4)));

#define B_CHUNK 64      // edge chunks (counting sort)
#define R_RANGE 2       // dst ranges per chunk (LDS hist = 50 KB, under 64 KB static cap)

__device__ __forceinline__ float exp2_fast(float x){
#if __has_builtin(__builtin_amdgcn_exp2f)
  return __builtin_amdgcn_exp2f(x);
#else
  return __expf(x * 0.69314718055994531f);
#endif
}
// update_dpp(0, src, ...) with bound_ctrl=1 folds into the consumer's dpp modifier
// (v_add_f32_dpp) instead of a separate v_mov_b32; worst case it's codegen-identical.
template<int CTRL>
__device__ __forceinline__ float dpp_add(float x){
  union { float f; int i; } a, b;
  a.f = x;
  b.i = __builtin_amdgcn_update_dpp(0, a.i, CTRL, 0xF, 0xF, true);
  return x + b.f;
}
__device__ __forceinline__ float sum4(float x){      // reduce within quad (one head)
  x = dpp_add<0xB1>(x);    // quad_perm [1,0,3,2]
  x = dpp_add<0x4E>(x);    // quad_perm [2,3,0,1]
  return x;
}
// single-instruction packed f32->bf16 (RNE), gfx950
__device__ __forceinline__ unsigned int cvt_pk_bf16(float lo, float hi){
  unsigned int r;
  asm("v_cvt_pk_bf16_f32 %0, %1, %2" : "=v"(r) : "v"(lo), "v"(hi));
  return r;
}
__device__ __forceinline__ unsigned short f2bf1(float f){
  return (unsigned short)cvt_pk_bf16(f, f);
}
__device__ __forceinline__ bf16x8 ld_bf8(const unsigned short* p){
  union { uint4 u; bf16x8 v; } c;
  c.u = *reinterpret_cast<const uint4*>(p);
  return c.v;
}
__device__ __forceinline__ bf16x8 ld_f32_to_bf8(const float* p){
  float4 lo = *reinterpret_cast<const float4*>(p);
  float4 hi = *reinterpret_cast<const float4*>(p + 4);
  union { unsigned int u[4]; bf16x8 v; } c;
  c.u[0] = cvt_pk_bf16(lo.x, lo.y);
  c.u[1] = cvt_pk_bf16(lo.z, lo.w);
  c.u[2] = cvt_pk_bf16(hi.x, hi.y);
  c.u[3] = cvt_pk_bf16(hi.z, hi.w);
  return c.v;
}

// ---------- K1: [S1 hist+rank | nbt type-bucket | W transpose->bf16] ----------
// S1: per (chunk,range) block, LDS histogram of dst; the atomicAdd's OLD VALUE is
// the edge's intra-chunk rank -> stored to rank[]. Makes the later scatter
// atomic-free and fully parallel. tcur pre-zeroed by hipMemsetAsync.
__global__ __launch_bounds__(256) void k_prep(const int* ntype, int* tcur, int* nbt,
                       int Npad, int N,
                       const float* subW, const float* neighW,
                       unsigned short* wts, unsigned short* wtn,
                       const int* ei, int E, unsigned short* hist,
                       unsigned short* rank, int RNG, int HR, int NB){
  __shared__ unsigned int lsh[12544];   // 25088 packed u16 bins (50 KB)
  int b = blockIdx.x;
  const int SB1 = B_CHUNK * R_RANGE;    // 128
  if (b < SB1){
    int cb = b & (B_CHUNK - 1);
    int r  = b >> 6;                    // B_CHUNK==64
    int lo = r * RNG;
    int bins = RNG >> 1;
    for (int i = threadIdx.x; i < bins; i += 256) lsh[i] = 0;
    __syncthreads();
    int C = (E + B_CHUNK - 1) / B_CHUNK;
    int e0 = cb * C;
    int e1 = e0 + C; if (e1 > E) e1 = E;
    for (int i = e0 + threadIdx.x; i < e1; i += 256){
      int d = ei[E + i] - lo;
      if ((unsigned)d < (unsigned)RNG){
        unsigned old = atomicAdd(&lsh[d >> 1], (d & 1) ? 65536u : 1u);
        rank[i] = (unsigned short)((old >> ((d & 1) << 4)) & 0xffffu);
      }
    }
    __syncthreads();
    unsigned int* hrow = reinterpret_cast<unsigned int*>(hist + (size_t)cb*HR + lo);
    for (int i = threadIdx.x; i < bins; i += 256) hrow[i] = lsh[i];
  } else if (b < SB1 + NB){
    int i = (b - SB1)*256 + threadIdx.x;
    if (i >= N) return;
    int lane = threadIdx.x & 63;
    int myt = ntype[i];
    unsigned long long below = (lane == 0) ? 0ull : ((~0ull) >> (64 - lane));
    #pragma unroll
    for (int tt = 0; tt < 4; ++tt){
      unsigned long long mask = __ballot(myt == tt);
      if (mask){
        int leader = __ffsll((long long)mask) - 1;
        int base = 0;
        if (lane == leader) base = atomicAdd(&tcur[tt], __popcll(mask));
        base = __shfl(base, leader);
        if (myt == tt){
          int pos = base + __popcll(mask & below);
          nbt[tt*Npad + pos] = i;
        }
      }
    }
  } else {
    int i = (b - SB1 - NB)*256 + threadIdx.x;   // 0 .. 131071
    int w = i >> 16;
    int r = i & 65535;
    int t = r >> 14;
    int rem = r & 16383;
    int o = rem >> 7;
    int kd = rem & 127;
    const float* src = w ? neighW : subW;
    unsigned short* dstp = w ? wtn : wts;
    dstp[(t << 14) + (o << 7) + kd] = f2bf1(src[(t << 14) + (kd << 7) + o]);
  }
}

// ---------- K2: [per-dst chunk-scan -> bases + deg | h proj] (LDS-free) ----------
__global__ __launch_bounds__(256) void k_mid(unsigned short* hist, int HR,
                       int* deg, int N, int SCB,
                       const float* h_mat, const float* hsW, const float* hsb,
                       const float* hnW, const float* hnb,
                       float2* hs2, char* hnc){
  int b = blockIdx.x;
  if (b < SCB){
    int d = b*256 + threadIdx.x;
    if (d >= N) return;
    unsigned run = 0;
    #pragma unroll 4
    for (int c = 0; c < B_CHUNK; ++c){
      unsigned short* p = hist + (size_t)c*HR + d;
      unsigned v = *p;
      *p = (unsigned short)run;
      run += v;
    }
    deg[d] = (int)run;
  } else {
    int i = (b - SCB)*256 + threadIdx.x;
    if (i >= N*32) return;
    int n = i >> 5, l = i & 31;
    const float* hm = h_mat + (size_t)n*8;
    const float2* hsW2 = reinterpret_cast<const float2*>(hsW);
    const float2* hnW2 = reinterpret_cast<const float2*>(hnW);
    float s0=0.f, s1=0.f, n0=0.f, n1=0.f;
    #pragma unroll
    for (int d = 0; d < 8; ++d){
      float hv = hm[d];
      float2 ws2 = hsW2[d*32 + l];
      float2 wn2 = hnW2[d*32 + l];
      s0 += hv * ws2.x; s1 += hv * ws2.y;
      n0 += hv * wn2.x; n1 += hv * wn2.y;
    }
    float2 bs = reinterpret_cast<const float2*>(hsb)[l];
    float2 bn = reinterpret_cast<const float2*>(hnb)[l];
    hs2[(size_t)i] = make_float2(s0 + bs.x, s1 + bs.y);
    *reinterpret_cast<unsigned int*>(hnc + (size_t)n*128 + l*4)
        = cvt_pk_bf16(n0 + bn.x, n1 + bn.y);
  }
}

// ---------- K3: [MFMA projections | atomic-free parallel scatter] (LDS-free) ----------
__global__ __launch_bounds__(256) void k_ms(const float* X,
      const unsigned short* wts, const unsigned short* wtn,   // bf16 [t][o][k]
      const float* sub_b, const float* neigh_b,
      const int* nbt, const int* tcur, int Npad,
      float* q, char* kkc,
      const int* ei, unsigned short* bucket, int E,
      const unsigned short* hist, int HR, const unsigned short* rank, int MB){
  int b = blockIdx.x;
  if (b < MB){
    // --- type-selected projections via MFMA 16x16x32 bf16, swapped operands:
    //     A = weight rows (o), B = node features -> C[row=o][col=node].
    //     Lane owns 4 consecutive output dims of one node -> float4 / 8B stores.
    int t = -1, chunk = 0, acc = 0;
    #pragma unroll
    for (int tt = 0; tt < 4; ++tt){
      int cnt = tcur[tt];
      int nc = (cnt + 63) >> 6;
      if (t < 0 && b < acc + nc){ t = tt; chunk = b - acc; }
      acc += nc;
    }
    if (t < 0) return;
    int lane = threadIdx.x & 63;
    int w = threadIdx.x >> 6;
    int quad = lane >> 4, l16 = lane & 15;
    int cnt = tcur[t];
    int p = chunk*64 + w*16 + l16;         // node slot (output column) for this lane
    bool ok = p < cnt;
    int nid = nbt[t*Npad + (ok ? p : 0)];
    bf16x8 xb[4];
    #pragma unroll
    for (int kk = 0; kk < 4; ++kk)
      xb[kk] = ld_f32_to_bf8(X + (size_t)nid*128 + kk*32 + quad*8);
    #pragma unroll
    for (int pj = 0; pj < 2; ++pj){
      const unsigned short* Wt = pj ? wtn : wts;
      const float* bias = pj ? neigh_b : sub_b;
      #pragma unroll
      for (int ot = 0; ot < 8; ++ot){
        f32x4 c = {0.f, 0.f, 0.f, 0.f};
        #pragma unroll
        for (int kk = 0; kk < 4; ++kk){
          bf16x8 wa = ld_bf8(Wt + ((size_t)t << 14) + ((size_t)(ot*16 + l16) << 7)
                                + kk*32 + quad*8);
          c = __builtin_amdgcn_mfma_f32_16x16x32_bf16(wa, xb[kk], c, 0, 0, 0);
        }
        int o0 = ot*16 + quad*4;           // 4 consecutive output dims for this lane
        float4 b4 = *reinterpret_cast<const float4*>(bias + t*128 + o0);
        if (ok){
          if (pj == 0){
            float4 v = make_float4(c[0]+b4.x, c[1]+b4.y, c[2]+b4.z, c[3]+b4.w);
            *reinterpret_cast<float4*>(q + (size_t)nid*128 + o0) = v;
          } else {
            uint2 pk;
            pk.x = cvt_pk_bf16(c[0]+b4.x, c[1]+b4.y);
            pk.y = cvt_pk_bf16(c[2]+b4.z, c[3]+b4.w);
            *reinterpret_cast<uint2*>(kkc + ((size_t)nid << 8) + (size_t)(o0 << 1)) = pk;
          }
        }
      }
    }
  } else {
    // --- scatter: pos = scanned base (this chunk) + intra-chunk rank. No atomics.
    int sb = b - MB;                 // 0 .. B_CHUNK*8-1
    int cb = sb >> 3;
    int sub = sb & 7;
    int C = (E + B_CHUNK - 1) / B_CHUNK;
    int seg = (C + 7) >> 3;
    int s0 = sub*seg;
    int s1 = s0 + seg; if (s1 > C) s1 = C;
    int e0 = cb*C + s0;
    int e1 = cb*C + s1; if (e1 > E) e1 = E;
    const unsigned short* hrow = hist + (size_t)cb*HR;
    for (int i = e0 + threadIdx.x; i < e1; i += 256){
      int d = ei[E + i];
      int pos = (int)hrow[d] + (int)rank[i];
      if (pos < 128) bucket[(size_t)d*128 + pos] = (unsigned short)ei[i];
    }
  }
}

// ---------- K4: per-dst-node wave, TWO edges per iteration (half-wave each).
//   lane l=0..31 owns k dims 4l..4l+3 (head=l>>2) and h dims 2l,2l+1.
//   Two dense gathers (8B k + 4B h) per lane per pair; one readlane per pair.
//   sum4 (fused-dpp) reduce, base-2 folded tanh/softmax with PAIRED rcp,
//   fused GELU + LayerNorm. ----------
__global__ __launch_bounds__(256) void k_edge(const float* q, const char* kkc,
      const char* hnc, const float2* hs2, const int* degA,
      const unsigned short* bucket, const int* ntype,
      const float* rel_att, const float* rel_h_att,
      const float* ln_g, const float* ln_b,
      float* out, int N){
  int wid = (blockIdx.x*blockDim.x + threadIdx.x) >> 6;
  if (wid >= N) return;
  int lane = threadIdx.x & 63;
  int l = lane & 31;
  int half = (lane >> 5) & 1;
  int t4 = l & 3, head = l >> 2;
  const float TLOG2E = 2.8853900817779268f;   // 2*log2(e)
  float4 qv = *reinterpret_cast<const float4*>(q + (size_t)wid*128 + l*4);
  float qe0 = qv.x*TLOG2E, qe1 = qv.y*TLOG2E, qe2 = qv.z*TLOG2E, qe3 = qv.w*TLOG2E;
  float2 hv = hs2[(size_t)wid*32 + l];
  float he0 = hv.x*TLOG2E, he1 = hv.y*TLOG2E;
  int st = ntype[wid];
  int rb = st*8 + head;
  float4 ra = *reinterpret_cast<const float4*>(rel_att + rb*16 + t4*4);
  float2 rh = *reinterpret_cast<const float2*>(rel_h_att + rb*8 + t4*2);
  // ra*tanh(x) = ra - 2*ra*rcp(exp2(c*x)+1); fold 1/sqrt(16)=0.25 into k-side,
  // 1/sqrt(8) and log2(e) (softmax exp2) into h-side.
  float c0 = -0.5f*ra.x, c1 = -0.5f*ra.y, c2 = -0.5f*ra.z, c3 = -0.5f*ra.w;
  float cs = 0.25f*(ra.x + ra.y + ra.z + ra.w);
  const float HSC = 0.35355339059327373f * 1.4426950408889634f;
  float rh0 = rh.x*HSC, rh1 = rh.y*HSC;
  float ch0 = -2.f*rh0, ch1 = -2.f*rh1, chs = rh0 + rh1;
  float s = 0.f, a0 = 0.f, a1 = 0.f, a2 = 0.f, a3 = 0.f;

  int deg = __builtin_amdgcn_readfirstlane(degA[wid]);
  if (deg > 128) deg = 128;
  unsigned bkt = reinterpret_cast<const unsigned*>(bucket)[(size_t)wid*64 + lane];
  int niter = (deg + 1) >> 1;
  const char* kk_l = kkc + l*8;
  const char* hn_l = hnc + l*4;

  struct KH { uint2 k; unsigned h; };
  auto lp = [&](int g)->KH {
    int gg = g < niter ? g : 0;                 // pipeline overfetch -> valid row
    unsigned v = (unsigned)__builtin_amdgcn_readlane((int)bkt, gg);
    int sA = (int)(v & 0xffffu);
    int sB = (2*gg + 1 < deg) ? (int)(v >> 16) : sA;   // odd tail -> duplicate A
    int sy = half ? sB : sA;
    KH r;
    r.k = *reinterpret_cast<const uint2*>(kk_l + ((size_t)(unsigned)sy << 8));
    r.h = *reinterpret_cast<const unsigned*>(hn_l + ((size_t)(unsigned)sy << 7));
    return r;
  };
  auto pr = [&](KH P, int g){
    union { unsigned u; float f; } k0,k1,k2,k3,h0,h1;
    k0.u = P.k.x << 16; k1.u = P.k.x & 0xffff0000u;
    k2.u = P.k.y << 16; k3.u = P.k.y & 0xffff0000u;
    h0.u = P.h << 16;   h1.u = P.h & 0xffff0000u;
    float e0 = exp2_fast(qe0*k0.f), e1 = exp2_fast(qe1*k1.f);
    float e2 = exp2_fast(qe2*k2.f), e3 = exp2_fast(qe3*k3.f);
    float f0 = exp2_fast(he0*h0.f), f1 = exp2_fast(he1*h1.f);
    // paired reciprocals: 1/d_a = d_b * rcp(d_a*d_b) — 3 rcp instead of 6.
    // (safe: exp2 overflow needs |q*k| > 44, never at these input scales)
    float d0 = e0 + 1.f, d1 = e1 + 1.f, d2 = e2 + 1.f, d3 = e3 + 1.f;
    float dh0 = f0 + 1.f, dh1 = f1 + 1.f;
    float R01 = __builtin_amdgcn_rcpf(d0*d1);
    float R23 = __builtin_amdgcn_rcpf(d2*d3);
    float Rh  = __builtin_amdgcn_rcpf(dh0*dh1);
    float r0 = d1*R01, r1 = d0*R01;
    float r2 = d3*R23, r3 = d2*R23;
    float g0 = dh1*Rh, g1 = dh0*Rh;
    float pp = fmaf(c0,r0, fmaf(c1,r1, fmaf(c2,r2, fmaf(c3,r3, cs))));
    float ph = fmaf(ch0,g0, fmaf(ch1,g1, chs));
    pp = sum4(pp);
    ph = sum4(ph);
    float w = exp2_fast(pp * ph);
    w = (2*g + half < deg) ? w : 0.f;
    s += w;
    a0 = fmaf(w, k0.f, a0); a1 = fmaf(w, k1.f, a1);
    a2 = fmaf(w, k2.f, a2); a3 = fmaf(w, k3.f, a3);
  };

  if (niter > 0){
    KH A = lp(0);
    KH B = lp(1);
    for (int g = 0; g < niter; g += 2){
      KH C = lp(g+2);
      pr(A, g);
      KH D = lp(g+3);
      if (g+1 < niter) pr(B, g+1);
      A = C; B = D;
    }
  }
  // merge the two half-wave edge streams
  s  += __shfl_xor(s, 32);
  a0 += __shfl_xor(a0, 32); a1 += __shfl_xor(a1, 32);
  a2 += __shfl_xor(a2, 32); a3 += __shfl_xor(a3, 32);

  float inv = 1.0f / (s + 1e-16f);
  float x0 = a0*inv, x1 = a1*inv, x2 = a2*inv, x3 = a3*inv;
  const float IS2 = 0.70710678118654752f;
  x0 = 0.5f*x0*(1.f + erff(x0*IS2));
  x1 = 0.5f*x1*(1.f + erff(x1*IS2));
  x2 = 0.5f*x2*(1.f + erff(x2*IS2));
  x3 = 0.5f*x3*(1.f + erff(x3*IS2));
  float sm = x0+x1+x2+x3;
  float sq = x0*x0 + x1*x1 + x2*x2 + x3*x3;
  #pragma unroll
  for (int d = 1; d < 32; d <<= 1){ sm += __shfl_xor(sm, d); sq += __shfl_xor(sq, d); }
  float mu = sm * (1.f/128.f);
  float var = fmaxf(sq * (1.f/128.f) - mu*mu, 0.f);
  float r = rsqrtf(var + 1e-5f);
  if (half == 0){
    float4 g4 = *reinterpret_cast<const float4*>(ln_g + l*4);
    float4 b4 = *reinterpret_cast<const float4*>(ln_b + l*4);
    float4 o4 = make_float4((x0-mu)*r*g4.x + b4.x, (x1-mu)*r*g4.y + b4.y,
                            (x2-mu)*r*g4.z + b4.z, (x3-mu)*r*g4.w + b4.w);
    *reinterpret_cast<float4*>(out + (size_t)wid*128 + l*4) = o4;
  }
}

extern "C" void kernel_launch(void* const* d_in, const int* in_sizes, int n_in,
                              void* d_out, int out_size, void* d_ws, size_t ws_size,
                              hipStream_t stream) {
  const float* meta_xs  = (const float*)d_in[0];
  const int*   node_type= (const int*)d_in[1];
  const int*   edge_idx = (const int*)d_in[2];
  const float* h_mat    = (const float*)d_in[3];
  const float* sub_W    = (const float*)d_in[4];
  const float* sub_b    = (const float*)d_in[5];
  const float* neigh_W  = (const float*)d_in[6];
  const float* neigh_b  = (const float*)d_in[7];
  const float* hsub_W   = (const float*)d_in[8];
  const float* hsub_b   = (const float*)d_in[9];
  const float* hneigh_W = (const float*)d_in[10];
  const float* hneigh_b = (const float*)d_in[11];
  const float* rel_att  = (const float*)d_in[12];
  const float* rel_hatt = (const float*)d_in[13];
  const float* ln_g     = (const float*)d_in[14];
  const float* ln_b     = (const float*)d_in[15];

  const int N = in_sizes[0] / 128;
  const int E = in_sizes[2] / 2;
  const int Npad = (N + 63) & ~63;
  // counting-sort geometry
  const int RNG = (((N + R_RANGE - 1) / R_RANGE) + 1) & ~1;   // even range width
  const int HR  = RNG * R_RANGE;                              // hist row stride (u16), >= N

  char* wbase = (char*)d_ws;
  size_t o = 0;
  auto carve = [&](size_t bytes)->char* {
    char* p = wbase + o;
    o = (o + bytes + 255) & ~(size_t)255;
    return p;
  };
  float*          q      = (float*)carve((size_t)N*128*4);
  char*           kkc    = carve((size_t)N*256);                 // k bf16[128] per node
  char*           hnc    = carve((size_t)N*128);                 // h bf16[64]  per node
  float2*         hs2    = (float2*)carve((size_t)N*32*8);
  unsigned short* bucket = (unsigned short*)carve((size_t)N*128*2);
  unsigned short* hist   = (unsigned short*)carve((size_t)B_CHUNK*HR*2);
  unsigned short* rank   = (unsigned short*)carve((size_t)E*2);
  int*            deg    = (int*)carve((size_t)N*4);
  int*            tmeta  = (int*)carve(64);                      // tcur[4]
  int*            nbt    = (int*)carve((size_t)4*Npad*4);
  unsigned short* wts    = (unsigned short*)carve((size_t)4*128*128*2);
  unsigned short* wtn    = (unsigned short*)carve((size_t)4*128*128*2);
  if (o > ws_size) return;

  int* tcur = tmeta;

  const int SB1 = B_CHUNK * R_RANGE;     // 128
  const int NB  = (N + 255) / 256;
  const int WB  = (2*4*128*128) / 256;   // 512
  const int SCB = (N + 255) / 256;
  const int HB  = (N*32 + 255) / 256;
  const int MB  = ((N + 63) >> 6) + 4;
  const int SB3 = B_CHUNK * 8;           // 512 scatter blocks

  hipMemsetAsync(tmeta, 0, 64, stream);
  k_prep <<<SB1 + NB + WB, 256, 0, stream>>>(node_type, tcur, nbt, Npad, N,
                                       sub_W, neigh_W, wts, wtn,
                                       edge_idx, E, hist, rank, RNG, HR, NB);
  k_mid  <<<SCB + HB, 256, 0, stream>>>(hist, HR, deg, N, SCB,
                                       h_mat, hsub_W, hsub_b, hneigh_W, hneigh_b,
                                       hs2, hnc);
  k_ms   <<<MB + SB3, 256, 0, stream>>>(meta_xs, wts, wtn, sub_b, neigh_b,
                                       nbt, tcur, Npad, q, kkc,
                                       edge_idx, bucket, E, hist, HR, rank, MB);
  k_edge <<<(N+3)/4, 256, 0, stream>>>(q, kkc, hnc, hs2, deg, bucket, node_type,
                                       rel_att, rel_hatt, ln_g, ln_b,
                                       (float*)d_out, N);
}